// Round 3
// baseline (123.011 us; speedup 1.0000x reference)
//
#include <hip/hip_runtime.h>

// pred_masks:   [B=8, NP=8, 512, 512] f32 logits
// target_masks: [B=8, NT=16, 512, 512] f32 in [0,1]
// out: scalar = 5 * mean_{b,i} min_j [ mean(softplus(p_i)) - <p_i,t_j>/HW ]
//      (all-zero targets j are skipped -> loss entry 0)
#define NB 8
#define NP 8
#define NT 16
#define HW (512 * 512)
#define HW4 (HW / 4)              // 65536 float4 per image
#define NACC (NP + NP * NT + NT)  // 152 accumulators per batch
#define THREADS 256
#define KITERS 8

__device__ __forceinline__ float softplus1(float x) {
  // stable: max(x,0) + log(1 + exp(-|x|)); hw exp/log, err ~1e-6.
  return fmaxf(x, 0.0f) + __logf(1.0f + __expf(-fabsf(x)));
}

__device__ __forceinline__ float wred(float v) {
#pragma unroll
  for (int off = 32; off > 0; off >>= 1) v += __shfl_down(v, off);
  return v;
}

// Pair-split streaming kernel: wave `jp` of a block handles target pair
// {2jp, 2jp+1} (16 dot accs + 2 target sums) plus softplus of pred image jp.
// 19 accumulators/thread, 11 loads/iter, NO barriers, NO LDS. Waves are
// fully independent: 6-step shuffle reduce then 19 atomicAdds per wave.
// Grid: blockIdx = ((b*128 + slice)<<1) | half; jp = half*4 + waveid.
// Each wave covers pixel float4 range [slice*512, slice*512+512).
__global__ __launch_bounds__(THREADS, 8) void sam_partial(
    const float* __restrict__ pred, const float* __restrict__ targ,
    float* __restrict__ ws) {
  const int lane  = threadIdx.x & 63;
  const int wid   = threadIdx.x >> 6;
  const int half  = blockIdx.x & 1;
  const int bs    = blockIdx.x >> 1;   // b*128 + slice
  const int b     = bs >> 7;
  const int slice = bs & 127;
  const int jp    = (half << 2) | wid; // 0..7

  const float4* __restrict__ pb =
      reinterpret_cast<const float4*>(pred) + (size_t)b * NP * HW4;
  const float4* __restrict__ t0b =
      reinterpret_cast<const float4*>(targ) + (size_t)(b * NT + 2 * jp) * HW4;
  const float4* __restrict__ t1b = t0b + HW4;
  const float4* __restrict__ pj = pb + (size_t)jp * HW4;

  float dot[NP][2];
#pragma unroll
  for (int i = 0; i < NP; ++i) { dot[i][0] = 0.0f; dot[i][1] = 0.0f; }
  float ts0 = 0.0f, ts1 = 0.0f, sp = 0.0f;

  int idx = slice * (64 * KITERS) + lane;
#pragma unroll 1
  for (int k = 0; k < KITERS; ++k, idx += 64) {
    const float4 t0 = t0b[idx];
    const float4 t1 = t1b[idx];
    ts0 += (t0.x + t0.y) + (t0.z + t0.w);
    ts1 += (t1.x + t1.y) + (t1.z + t1.w);
    // preds in two halves of 4 to keep live set ~50 VGPRs
#pragma unroll
    for (int h = 0; h < 2; ++h) {
      float4 p[4];
#pragma unroll
      for (int u = 0; u < 4; ++u) p[u] = pb[(size_t)(h * 4 + u) * HW4 + idx];
#pragma unroll
      for (int u = 0; u < 4; ++u) {
        const int i = h * 4 + u;
        dot[i][0] = fmaf(p[u].x, t0.x, fmaf(p[u].y, t0.y,
                    fmaf(p[u].z, t0.z, fmaf(p[u].w, t0.w, dot[i][0]))));
        dot[i][1] = fmaf(p[u].x, t1.x, fmaf(p[u].y, t1.y,
                    fmaf(p[u].z, t1.z, fmaf(p[u].w, t1.w, dot[i][1]))));
      }
    }
    // softplus for pred image jp: reload (guaranteed L1 hit, avoids branches)
    const float4 q = pj[idx];
    sp += (softplus1(q.x) + softplus1(q.y)) + (softplus1(q.z) + softplus1(q.w));
  }

  // Wave reduction + atomics (no cross-wave interaction).
  float* wb = ws + (size_t)b * NACC;
  {
    const float v = wred(sp);
    if (lane == 0) atomicAdd(wb + jp, v);
  }
#pragma unroll
  for (int i = 0; i < NP; ++i) {
#pragma unroll
    for (int jj = 0; jj < 2; ++jj) {
      const float v = wred(dot[i][jj]);
      if (lane == 0) atomicAdd(wb + NP + i * NT + 2 * jp + jj, v);
    }
  }
  {
    const float v = wred(ts0);
    if (lane == 0) atomicAdd(wb + NP + NP * NT + 2 * jp, v);
  }
  {
    const float v = wred(ts1);
    if (lane == 0) atomicAdd(wb + NP + NP * NT + 2 * jp + 1, v);
  }
}

// Stage 2: one wave; thread t owns (b = t>>3, i = t&7).
__global__ void sam_final(const float* __restrict__ ws,
                          float* __restrict__ out) {
  const int t = threadIdx.x;  // 64 threads
  const int b = t >> 3;
  const int i = t & 7;
  const float* w = ws + (size_t)b * NACC;
  const float spsum = w[i];
  float m = 3.4e38f;
#pragma unroll
  for (int j = 0; j < NT; ++j) {
    const float tsj = w[NP + NP * NT + j];
    const float v =
        (tsj == 0.0f) ? 0.0f : (spsum - w[NP + i * NT + j]) * (1.0f / HW);
    m = fminf(m, v);
  }
  float s = m;
#pragma unroll
  for (int off = 32; off > 0; off >>= 1) s += __shfl_down(s, off);
  if (t == 0) out[0] = 5.0f * s * (1.0f / 64.0f);
}

extern "C" void kernel_launch(void* const* d_in, const int* in_sizes, int n_in,
                              void* d_out, int out_size, void* d_ws,
                              size_t ws_size, hipStream_t stream) {
  const float* pred = (const float*)d_in[0];
  const float* targ = (const float*)d_in[1];
  float* out = (float*)d_out;
  float* ws = (float*)d_ws;

  hipMemsetAsync(ws, 0, (size_t)NB * NACC * sizeof(float), stream);
  sam_partial<<<dim3(NB * 128 * 2), THREADS, 0, stream>>>(pred, targ, ws);
  sam_final<<<1, 64, 0, stream>>>(ws, out);
}

// Round 4
// 115.252 us; speedup vs baseline: 1.0673x; 1.0673x over previous
//
#include <hip/hip_runtime.h>
#include <stdint.h>

// pred_masks:   [B=8, NP=8, 512, 512] f32 logits
// target_masks: [B=8, NT=16, 512, 512] f32 in [0,1]
// out: scalar = 5 * mean_{b,i} min_j [ mean(softplus(p_i)) - <p_i,t_j>/HW ]
//      (all-zero targets j are skipped -> loss entry 0)
#define NB 8
#define NP 8
#define NT 16
#define NIMG (NP + NT)            // 24 images per batch
#define HW (512 * 512)
#define CH 256                    // floats per image-chunk (1 KiB)
#define NCH (HW / CH)             // 1024 chunks per image
#define THREADS 512               // 8 waves
#define CPB 8                     // chunk-iters per block
#define NACC (NP + NP * NT + NT)  // 152

__device__ __forceinline__ void gload_lds16(const float* g, float* l) {
  // async global->LDS, 16B/lane; LDS dest = wave-uniform base + lane*16.
  __builtin_amdgcn_global_load_lds(
      (const __attribute__((address_space(1))) void*)g,
      (__attribute__((address_space(3))) void*)l, 16, 0, 0);
}

__device__ __forceinline__ float softplus1(float x) {
  return fmaxf(x, 0.0f) + __logf(1.0f + __expf(-fabsf(x)));
}

__device__ __forceinline__ float wred(float v) {
#pragma unroll
  for (int off = 32; off > 0; off >>= 1) v += __shfl_down(v, off);
  return v;
}

// Cooperative-staging kernel. Per chunk-iter: 8 waves stage 24 x 1KiB image
// chunks into LDS (3 global_load_lds_dwordx4 per wave, contiguous), barrier,
// then wave jp accumulates dots for target pair {2jp,2jp+1} x all 8 preds,
// target sums, and softplus of pred jp — all operands from LDS. Each input
// byte is fetched from global exactly once per covering block.
__global__ __launch_bounds__(THREADS, 8) void sam_partial(
    const float* __restrict__ pred, const float* __restrict__ targ,
    float* __restrict__ ws) {
  const int tid  = threadIdx.x;
  const int lane = tid & 63;
  const int wid  = tid >> 6;  // wave id = pair id jp
  __shared__ float lds[NIMG * CH];  // 24 KiB

  float dot[NP][2];
#pragma unroll
  for (int i = 0; i < NP; ++i) { dot[i][0] = 0.0f; dot[i][1] = 0.0f; }
  float ts0 = 0.0f, ts1 = 0.0f, sp = 0.0f;

  const float4* l4 = reinterpret_cast<const float4*>(lds);

#pragma unroll 1
  for (int k = 0; k < CPB; ++k) {
    const int G = blockIdx.x * CPB + k;  // global chunk-iter
    const int b = G >> 10;               // G / NCH
    const int c = G & (NCH - 1);

    // ---- stage: wave w loads image-chunks {w, w+8, w+16} ----
#pragma unroll
    for (int r = 0; r < 3; ++r) {
      const int m = r * 8 + wid;  // image 0..23 (0-7 pred, 8-23 targ)
      const float* base =
          (m < NP) ? pred + ((size_t)b * NP + m) * HW
                   : targ + ((size_t)b * NT + (m - NP)) * HW;
      gload_lds16(base + (size_t)c * CH + lane * 4, &lds[m * CH]);
    }
    asm volatile("s_waitcnt vmcnt(0)" ::: "memory");
    __syncthreads();

    // ---- compute from LDS ----
    float4 p[NP];
#pragma unroll
    for (int i = 0; i < NP; ++i) p[i] = l4[i * (CH / 4) + lane];
    const float4 t0 = l4[(NP + 2 * wid) * (CH / 4) + lane];
    const float4 t1 = l4[(NP + 2 * wid + 1) * (CH / 4) + lane];
    const float4 q  = l4[wid * (CH / 4) + lane];  // own pred (runtime wid -> LDS, not reg-array)

    ts0 += (t0.x + t0.y) + (t0.z + t0.w);
    ts1 += (t1.x + t1.y) + (t1.z + t1.w);
#pragma unroll
    for (int i = 0; i < NP; ++i) {
      dot[i][0] = fmaf(p[i].x, t0.x, fmaf(p[i].y, t0.y,
                  fmaf(p[i].z, t0.z, fmaf(p[i].w, t0.w, dot[i][0]))));
      dot[i][1] = fmaf(p[i].x, t1.x, fmaf(p[i].y, t1.y,
                  fmaf(p[i].z, t1.z, fmaf(p[i].w, t1.w, dot[i][1]))));
    }
    sp += (softplus1(q.x) + softplus1(q.y)) + (softplus1(q.z) + softplus1(q.w));
    __syncthreads();  // protect LDS before next stage
  }

  // ---- wave-level reduce + atomics (block's chunks are one batch: b fixed) ----
  const int b = (blockIdx.x * CPB) >> 10;
  float* wb = ws + (size_t)b * NACC;
  {
    const float v = wred(sp);
    if (lane == 0) atomicAdd(wb + wid, v);
  }
#pragma unroll
  for (int i = 0; i < NP; ++i) {
#pragma unroll
    for (int jj = 0; jj < 2; ++jj) {
      const float v = wred(dot[i][jj]);
      if (lane == 0) atomicAdd(wb + NP + i * NT + 2 * wid + jj, v);
    }
  }
  {
    const float v = wred(ts0);
    if (lane == 0) atomicAdd(wb + NP + NP * NT + 2 * wid, v);
  }
  {
    const float v = wred(ts1);
    if (lane == 0) atomicAdd(wb + NP + NP * NT + 2 * wid + 1, v);
  }
}

// Stage 2: one wave; thread t owns (b = t>>3, i = t&7).
__global__ void sam_final(const float* __restrict__ ws,
                          float* __restrict__ out) {
  const int t = threadIdx.x;  // 64 threads
  const int b = t >> 3;
  const int i = t & 7;
  const float* w = ws + (size_t)b * NACC;
  const float spsum = w[i];
  float m = 3.4e38f;
#pragma unroll
  for (int j = 0; j < NT; ++j) {
    const float tsj = w[NP + NP * NT + j];
    const float v =
        (tsj == 0.0f) ? 0.0f : (spsum - w[NP + i * NT + j]) * (1.0f / HW);
    m = fminf(m, v);
  }
  float s = m;
#pragma unroll
  for (int off = 32; off > 0; off >>= 1) s += __shfl_down(s, off);
  if (t == 0) out[0] = 5.0f * s * (1.0f / 64.0f);
}

extern "C" void kernel_launch(void* const* d_in, const int* in_sizes, int n_in,
                              void* d_out, int out_size, void* d_ws,
                              size_t ws_size, hipStream_t stream) {
  const float* pred = (const float*)d_in[0];
  const float* targ = (const float*)d_in[1];
  float* out = (float*)d_out;
  float* ws = (float*)d_ws;

  hipMemsetAsync(ws, 0, (size_t)NB * NACC * sizeof(float), stream);
  const int grid = NB * NCH / CPB;  // 1024 blocks, 4 per CU
  sam_partial<<<dim3(grid), THREADS, 0, stream>>>(pred, targ, ws);
  sam_final<<<1, 64, 0, stream>>>(ws, out);
}

// Round 5
// 75.149 us; speedup vs baseline: 1.6369x; 1.5336x over previous
//
#include <hip/hip_runtime.h>

// pred_masks:   [B=8, NP=8, 512, 512] f32 logits
// target_masks: [B=8, NT=16, 512, 512] f32 in [0,1]
// out: scalar = 5 * mean_{b,i} min_j [ mean(softplus(p_i)) - <p_i,t_j>/HW ]
//      (all-zero targets j are skipped -> loss entry 0)
#define NB 8
#define NP 8
#define NT 16
#define HW (512 * 512)
#define HW4 (HW / 4)              // 65536 float4 per image
#define NACC (NP + NP * NT + NT)  // 152 accumulators per batch
#define BLOCKS_PER_B 64
#define THREADS 256
#define ITERS 4                   // 64 blocks * 256 thr * 4 iters = 65536 = HW4
#define TWIN 8                    // rolling window of in-flight target loads

__device__ __forceinline__ float wred(float v) {
#pragma unroll
  for (int off = 32; off > 0; off >>= 1) v += __shfl_down(v, off);
  return v;
}

__device__ __forceinline__ float softplus1(float x) {
  // stable: max(x,0) + log(1 + exp(-|x|)); hw exp/log, err ~1e-6 rel.
  return fmaxf(x, 0.0f) + __logf(1.0f + __expf(-fabsf(x)));
}

// Stage 1: R0 chassis (24 streams per thread, 152 accumulators) + an 8-deep
// rolling register window on the target stream so ~8 KiB/wave stays in
// flight through the whole consume phase (R0 reused 4 VGPRs for all 16
// t-loads -> WAR-serialized at one memory latency per load).
__global__ __launch_bounds__(THREADS, 2) void sam_partial(
    const float* __restrict__ pred, const float* __restrict__ targ,
    float* __restrict__ ws) {
  const int b   = blockIdx.x / BLOCKS_PER_B;
  const int blk = blockIdx.x % BLOCKS_PER_B;
  const int tid = threadIdx.x;

  float sp[NP];
  float ts[NT];
  float dot[NP][NT];
#pragma unroll
  for (int i = 0; i < NP; ++i) sp[i] = 0.0f;
#pragma unroll
  for (int j = 0; j < NT; ++j) ts[j] = 0.0f;
#pragma unroll
  for (int i = 0; i < NP; ++i)
#pragma unroll
    for (int j = 0; j < NT; ++j) dot[i][j] = 0.0f;

  const float4* __restrict__ pb =
      reinterpret_cast<const float4*>(pred) + (size_t)b * NP * HW4;
  const float4* __restrict__ tb =
      reinterpret_cast<const float4*>(targ) + (size_t)b * NT * HW4;

#pragma unroll 1
  for (int it = 0; it < ITERS; ++it) {
    const int idx = blk * (THREADS * ITERS) + it * THREADS + tid;

    // Issue all 8 pred loads + prime the 8-deep target window: 16 loads in
    // flight before the first consume.
    float4 p[NP];
#pragma unroll
    for (int i = 0; i < NP; ++i) p[i] = pb[(size_t)i * HW4 + idx];
    float4 twin[TWIN];
#pragma unroll
    for (int j = 0; j < TWIN; ++j) twin[j] = tb[(size_t)j * HW4 + idx];

    // Consume t[j]; immediately refill the slot with t[j+TWIN] (static
    // indices -> registers; window keeps ~TWIN loads outstanding).
#pragma unroll
    for (int j = 0; j < NT; ++j) {
      const float4 t = twin[j % TWIN];
      if (j + TWIN < NT) twin[j % TWIN] = tb[(size_t)(j + TWIN) * HW4 + idx];
      ts[j] += (t.x + t.y) + (t.z + t.w);
#pragma unroll
      for (int i = 0; i < NP; ++i) {
        dot[i][j] = fmaf(p[i].x, t.x,
                    fmaf(p[i].y, t.y,
                    fmaf(p[i].z, t.z,
                    fmaf(p[i].w, t.w, dot[i][j]))));
      }
    }
    // Softplus from the still-live pred registers.
#pragma unroll
    for (int i = 0; i < NP; ++i) {
      sp[i] += (softplus1(p[i].x) + softplus1(p[i].y)) +
               (softplus1(p[i].z) + softplus1(p[i].w));
    }
  }

  // Block reduction: wave shuffle-reduce each accumulator, stash wave sums in
  // LDS, then threads 0..NACC-1 fold 4 waves and atomicAdd to global ws.
  __shared__ float red[4][NACC];
  const int lane = tid & 63;
  const int wid  = tid >> 6;

#pragma unroll
  for (int i = 0; i < NP; ++i) {
    float v = wred(sp[i]);
    if (lane == 0) red[wid][i] = v;
  }
#pragma unroll
  for (int i = 0; i < NP; ++i) {
#pragma unroll
    for (int j = 0; j < NT; ++j) {
      float v = wred(dot[i][j]);
      if (lane == 0) red[wid][NP + i * NT + j] = v;
    }
  }
#pragma unroll
  for (int j = 0; j < NT; ++j) {
    float v = wred(ts[j]);
    if (lane == 0) red[wid][NP + NP * NT + j] = v;
  }
  __syncthreads();
  if (tid < NACC) {
    float v = (red[0][tid] + red[1][tid]) + (red[2][tid] + red[3][tid]);
    atomicAdd(ws + (size_t)b * NACC + tid, v);
  }
}

// Stage 2: one wave; thread t owns (b = t>>3, i = t&7).
__global__ void sam_final(const float* __restrict__ ws,
                          float* __restrict__ out) {
  const int t = threadIdx.x;  // 64 threads
  const int b = t >> 3;
  const int i = t & 7;
  const float* w = ws + (size_t)b * NACC;
  const float spsum = w[i];
  float m = 3.4e38f;
#pragma unroll
  for (int j = 0; j < NT; ++j) {
    const float tsj = w[NP + NP * NT + j];
    const float v =
        (tsj == 0.0f) ? 0.0f : (spsum - w[NP + i * NT + j]) * (1.0f / HW);
    m = fminf(m, v);
  }
  float s = m;
#pragma unroll
  for (int off = 32; off > 0; off >>= 1) s += __shfl_down(s, off);
  if (t == 0) out[0] = 5.0f * s * (1.0f / 64.0f);
}

extern "C" void kernel_launch(void* const* d_in, const int* in_sizes, int n_in,
                              void* d_out, int out_size, void* d_ws,
                              size_t ws_size, hipStream_t stream) {
  const float* pred = (const float*)d_in[0];
  const float* targ = (const float*)d_in[1];
  float* out = (float*)d_out;
  float* ws = (float*)d_ws;

  hipMemsetAsync(ws, 0, (size_t)NB * NACC * sizeof(float), stream);
  sam_partial<<<dim3(NB * BLOCKS_PER_B), THREADS, 0, stream>>>(pred, targ, ws);
  sam_final<<<1, 64, 0, stream>>>(ws, out);
}